// Round 8
// baseline (4717.430 us; speedup 1.0000x reference)
//
#include <hip/hip_runtime.h>
#include <hip/hip_bf16.h>

// EA-LSTM for MI355X (gfx950), round 8: chunked two-phase design.
// ws layout: [0,64K) h-state bf16[128][256]; [64K,192K) c-state f32[128][256];
//            [256K, 256K + T_C*256K) P chunk buffer.
// For each time chunk: precomp_kernel writes P[b][tloc][g][pos] (bf16
// x-projections + biases for f,g,o; sigm(i)); ealstm_rec consumes it.
// Rec: 32 WGs x 256 thr (4 waves, 1 wave/SIMD, 512-reg budget). Wave w owns
// channels [w*64,(w+1)*64); batch row b staged at A-row 4b so MFMA D r==0
// gives one gate-set per (lane,nt) with no redistribution.
// Weights: f,g all 8 K-steps + o K-steps 3..7 in regs; o K-steps 0..2 in LDS.
// Fallback (ws < 32.2 MiB): round-6 kernel (proven, 4060 us).

#define T_LEN 2048
#define HD 256

typedef __attribute__((ext_vector_type(8))) short bf16x8;
typedef __attribute__((ext_vector_type(4))) float f32x4;
typedef __attribute__((ext_vector_type(2))) unsigned int u32x2;

#define LOG2E 1.4426950408889634f

__device__ __forceinline__ short f2bf(float f) {
  unsigned u = __float_as_uint(f);
  unsigned r = (u + 0x7fffu + ((u >> 16) & 1u)) >> 16;
  return (short)r;
}

__device__ __forceinline__ bf16x8 loadw8(const float* p) {
  bf16x8 r;
#pragma unroll
  for (int i = 0; i < 8; ++i) r[i] = f2bf(p[i]);
  return r;
}

__device__ __forceinline__ float sigm(float x) {
  float e = __builtin_amdgcn_exp2f(-LOG2E * x);
  return __builtin_amdgcn_rcpf(1.0f + e);
}

// clamp-free tanh: 1 - 2/(e^{2x}+1); saturates to +/-1, NaN-free.
__device__ __forceinline__ float tanh_(float x) {
  float e = __builtin_amdgcn_exp2f((2.0f * LOG2E) * x);
  return 1.0f - 2.0f * __builtin_amdgcn_rcpf(e + 1.0f);
}

// unpack bf16 element nt (0..3) from an 8-byte packed pair of dwords
__device__ __forceinline__ float punp(u32x2 p, int nt) {
  unsigned d = (nt < 2) ? p[0] : p[1];
  unsigned s = (nt & 1) ? (d & 0xffff0000u) : (d << 16);
  return __uint_as_float(s);
}

// ============================ phase 1: precompute ============================
// P local layout: ((b*tlen + (t-t0))*4 + g)*256 + pos, pos = w*64 + lr*4 + nt
// holding channel ch = w*64 + nt*16 + lr.
__global__ __launch_bounds__(256) void precomp_kernel(
    const float* __restrict__ x,
    const float* __restrict__ Wi,  const float* __restrict__ bi,
    const float* __restrict__ Wfx, const float* __restrict__ bfx, const float* __restrict__ bfh,
    const float* __restrict__ Wgx, const float* __restrict__ bgx, const float* __restrict__ bgh,
    const float* __restrict__ Wox, const float* __restrict__ box_, const float* __restrict__ boh,
    unsigned short* __restrict__ P, int t0, int tlen)
{
  const int tid = threadIdx.x;
  const int b   = blockIdx.x;       // 0..127
  const int w   = tid >> 6;
  const int lr  = (tid >> 2) & 15;
  const int nt  = tid & 3;
  const int ch  = w * 64 + nt * 16 + lr;

  float wf[8], wg[8], wo[8], wi[24];
#pragma unroll
  for (int d = 0; d < 8; ++d) {
    wf[d] = Wfx[ch * 8 + d];
    wg[d] = Wgx[ch * 8 + d];
    wo[d] = Wox[ch * 8 + d];
  }
#pragma unroll
  for (int d = 0; d < 24; ++d) wi[d] = Wi[ch * 24 + d];
  const float cf = bfx[ch] + bfh[ch];
  const float cg = bgx[ch] + bgh[ch];
  const float co = box_[ch] + boh[ch];
  const float ci = bi[ch];

  __shared__ float xs[32];
  const int tb = t0 + blockIdx.y * 128;
  for (int t = tb; t < tb + 128; ++t) {
    __syncthreads();
    if (tid < 32) xs[tid] = x[((size_t)b * T_LEN + t) * 32 + tid];
    __syncthreads();
    float fv = cf, gv = cg, ov = co, iv = ci;
#pragma unroll
    for (int d = 0; d < 8; ++d) {
      fv += xs[d] * wf[d];
      gv += xs[d] * wg[d];
      ov += xs[d] * wo[d];
    }
#pragma unroll
    for (int d = 0; d < 24; ++d) iv += xs[8 + d] * wi[d];
    iv = sigm(iv);
    unsigned short* Pp = P + ((size_t)b * tlen + (t - t0)) * 1024;
    Pp[0 * 256 + tid] = (unsigned short)f2bf(fv);
    Pp[1 * 256 + tid] = (unsigned short)f2bf(gv);
    Pp[2 * 256 + tid] = (unsigned short)f2bf(ov);
    Pp[3 * 256 + tid] = (unsigned short)f2bf(iv);
  }
}

// ============================ phase 2: recurrence ============================
// A tile: 16 rows x 264 cols bf16 (h only). Valid rows at {0,4,8,12}.
#define ASTR 264
#define ABUF (16 * ASTR)

__global__ __launch_bounds__(256, 1) void ealstm_rec(
    const unsigned short* __restrict__ P,
    const float* __restrict__ c0, const float* __restrict__ h0,
    unsigned short* __restrict__ hs, float* __restrict__ cs,
    const float* __restrict__ Wfh, const float* __restrict__ Wgh, const float* __restrict__ Woh,
    const float* __restrict__ Wout, const float* __restrict__ bout,
    float* __restrict__ out, int t0, int tlen, int first)
{
  __shared__ __attribute__((aligned(16))) short A_sh[2 * ABUF];          // 16896 B
  __shared__ __attribute__((aligned(16))) short Bo_sh[4 * 3 * 4 * 512];  // 49152 B
  __shared__ float out_part[2][4][4];                                    // 128 B

  const int tid = threadIdx.x;
  const int w   = tid >> 6;   // wave 0..3, owns ch [w*64, w*64+64)
  const int l   = tid & 63;
  const int lr  = l & 15;
  const int lg  = l >> 4;     // activation row = lg (A-row trick)
  const int wg  = blockIdx.x; // 4-row batch block

  // ---- register-resident weights: f,g all K-steps; o K-steps 3..7 ----
  bf16x8 Bf[8][4], Bg[8][4], BoR[5][4];
#pragma unroll
  for (int ks = 0; ks < 8; ++ks) {
#pragma unroll
    for (int nt = 0; nt < 4; ++nt) {
      const int n = w * 64 + nt * 16 + lr;
      const int k = ks * 32 + lg * 8;
      Bf[ks][nt] = loadw8(Wfh + n * HD + k);
      Bg[ks][nt] = loadw8(Wgh + n * HD + k);
    }
  }
#pragma unroll
  for (int ks = 3; ks < 8; ++ks) {
#pragma unroll
    for (int nt = 0; nt < 4; ++nt) {
      const int n = w * 64 + nt * 16 + lr;
      BoR[ks - 3][nt] = loadw8(Woh + n * HD + ks * 32 + lg * 8);
    }
  }
  // ---- LDS-resident: o K-steps 0..2 ----
  short* bo = Bo_sh + w * (3 * 4 * 512);
#pragma unroll
  for (int ks = 0; ks < 3; ++ks) {
#pragma unroll
    for (int nt = 0; nt < 4; ++nt) {
      const int n = w * 64 + nt * 16 + lr;
      bf16x8 fr = loadw8(Woh + n * HD + ks * 32 + lg * 8);
      *reinterpret_cast<bf16x8*>(bo + (ks * 4 + nt) * 512 + l * 8) = fr;
    }
  }

  // ---- Wout, c-state (per-lane: row lg, 4 nt channels) ----
  float woutv[4], cst[4];
#pragma unroll
  for (int nt = 0; nt < 4; ++nt) {
    const int n = w * 64 + nt * 16 + lr;
    woutv[nt] = Wout[n];
    cst[nt]   = first ? c0[n] : cs[(size_t)(wg * 4 + lg) * 256 + n];
  }
  const float boutv = bout[0];

  // ---- zero both A buffers; stage h-state at A-rows {0,4,8,12} ----
  for (int idx = tid; idx < 2 * ABUF; idx += 256) A_sh[idx] = 0;
  __syncthreads();
  for (int idx = tid; idx < 4 * 256; idx += 256) {
    const int row = idx >> 8, col = idx & 255;
    const short hv = first ? f2bf(h0[col])
                           : (short)hs[(size_t)(wg * 4 + row) * 256 + col];
    A_sh[(4 * row) * ASTR + col] = hv;
  }
  __syncthreads();

  // per-lane P pointer: row = wg*4 + lg, lane offset w*64 + lr*4
  const unsigned short* Pl = P + ((size_t)(wg * 4 + lg) * tlen) * 1024 + (w * 64 + lr * 4);
  const int akoff = lg * 8;

  // prefetch P for local t=0
  u32x2 pc[4], pn[4];
#pragma unroll
  for (int g = 0; g < 4; ++g) {
    pc[g] = *reinterpret_cast<const u32x2*>(Pl + g * 256);
  }

#pragma unroll 2
  for (int t = 0; t < tlen; ++t) {
    const int cur = t & 1;
    const short* ArowC = A_sh + cur * ABUF + lr * ASTR;
    short* Anxt = A_sh + (cur ^ 1) * ABUF;

    // prefetch P for t+1 (clamped)
    {
      const int tn = (t + 1 < tlen) ? (t + 1) : (tlen - 1);
      const unsigned short* Pt = Pl + (size_t)tn * 1024;
#pragma unroll
      for (int g = 0; g < 4; ++g) {
        pn[g] = *reinterpret_cast<const u32x2*>(Pt + g * 256);
      }
    }

    // finalize previous step's output (hidden under this step's MFMA phase)
    if (t > 0 && w == 0 && l < 4) {
      float s = boutv;
#pragma unroll
      for (int ww = 0; ww < 4; ++ww) s += out_part[cur ^ 1][l][ww];
      out[(size_t)(wg * 4 + l) * T_LEN + (t0 + t - 1)] = s;
    }

    // accumulators (zero; biases live in P)
    f32x4 acc[3][4];
#pragma unroll
    for (int g = 0; g < 3; ++g) {
#pragma unroll
      for (int nt = 0; nt < 4; ++nt) {
        f32x4 v; v[0] = 0.f; v[1] = 0.f; v[2] = 0.f; v[3] = 0.f;
        acc[g][nt] = v;
      }
    }

    // ---- merged K-loop: 1 A-read -> 12 MFMAs ----
#pragma unroll
    for (int ks = 0; ks < 8; ++ks) {
      const bf16x8 a = *reinterpret_cast<const bf16x8*>(ArowC + ks * 32 + akoff);
#pragma unroll
      for (int nt = 0; nt < 4; ++nt) {
        acc[0][nt] = __builtin_amdgcn_mfma_f32_16x16x32_bf16(a, Bf[ks][nt], acc[0][nt], 0, 0, 0);
      }
#pragma unroll
      for (int nt = 0; nt < 4; ++nt) {
        acc[1][nt] = __builtin_amdgcn_mfma_f32_16x16x32_bf16(a, Bg[ks][nt], acc[1][nt], 0, 0, 0);
      }
      if (ks < 3) {
#pragma unroll
        for (int nt = 0; nt < 4; ++nt) {
          const bf16x8 b = *reinterpret_cast<const bf16x8*>(bo + (ks * 4 + nt) * 512 + l * 8);
          acc[2][nt] = __builtin_amdgcn_mfma_f32_16x16x32_bf16(a, b, acc[2][nt], 0, 0, 0);
        }
      } else {
#pragma unroll
        for (int nt = 0; nt < 4; ++nt) {
          acc[2][nt] = __builtin_amdgcn_mfma_f32_16x16x32_bf16(a, BoR[ks - 3][nt], acc[2][nt], 0, 0, 0);
        }
      }
    }

    // ---- activations: 4 gate-sets per lane (row = lg, ch = w*64 + nt*16 + lr) ----
    float po = 0.0f;
#pragma unroll
    for (int nt = 0; nt < 4; ++nt) {
      const float fpre = acc[0][nt][0] + punp(pc[0], nt);
      const float gpre = acc[1][nt][0] + punp(pc[1], nt);
      const float opre = acc[2][nt][0] + punp(pc[2], nt);
      const float iv   = punp(pc[3], nt);  // sigmoid already applied
      const float sf = sigm(fpre);
      const float tg = tanh_(gpre);
      const float so = sigm(opre);
      const float c  = sf * cst[nt] + iv * tg;
      cst[nt] = c;
      const float hv = so * tanh_(c);
      Anxt[(4 * lg) * ASTR + (w * 64 + nt * 16 + lr)] = f2bf(hv);
      po += so * woutv[nt];
    }

    // po reduce over the 16 lr-lanes -> (row = lg, wave w)
#pragma unroll
    for (int mk = 1; mk < 16; mk <<= 1) {
      po += __shfl_xor(po, mk, 64);
    }
    if (lr == 0) out_part[cur][lg][w] = po;

    // roll P prefetch
#pragma unroll
    for (int g = 0; g < 4; ++g) pc[g] = pn[g];

    __syncthreads();  // single per-step barrier
  }

  // final output of the chunk
  if (w == 0 && l < 4) {
    float s = boutv;
#pragma unroll
    for (int ww = 0; ww < 4; ++ww) s += out_part[(tlen - 1) & 1][l][ww];
    out[(size_t)(wg * 4 + l) * T_LEN + (t0 + tlen - 1)] = s;
  }

  // ---- persist c/h state for the next chunk ----
  {
    const short* Afin = A_sh + (tlen & 1) * ABUF;  // last h written into buffer tlen&1
#pragma unroll
    for (int nt = 0; nt < 4; ++nt) {
      const int n = w * 64 + nt * 16 + lr;
      hs[(size_t)(wg * 4 + lg) * 256 + n] = (unsigned short)Afin[(4 * lg) * ASTR + n];
      cs[(size_t)(wg * 4 + lg) * 256 + n] = cst[nt];
    }
  }
}

// ============================ fallback: round-6 kernel ============================
#define FASTR 296
#define FABUF (16 * FASTR)

__global__ __launch_bounds__(512, 2) void ealstm_fallback(
    const float* __restrict__ x, const float* __restrict__ c0, const float* __restrict__ h0,
    const float* __restrict__ Wi, const float* __restrict__ bi,
    const float* __restrict__ Wfx, const float* __restrict__ bfx,
    const float* __restrict__ Wfh, const float* __restrict__ bfh,
    const float* __restrict__ Wgx, const float* __restrict__ bgx,
    const float* __restrict__ Wgh, const float* __restrict__ bgh,
    const float* __restrict__ Wox, const float* __restrict__ box_,
    const float* __restrict__ Woh, const float* __restrict__ boh,
    const float* __restrict__ Wout, const float* __restrict__ bout,
    float* __restrict__ out)
{
  __shared__ __attribute__((aligned(16))) short A_sh[2 * FABUF];
  __shared__ __attribute__((aligned(16))) short Bo_sh[8 * 16 * 512];
  __shared__ float out_part[2][4][8];

  const int tid = threadIdx.x;
  const int w   = tid >> 6;
  const int l   = tid & 63;
  const int lr  = l & 15;
  const int lg  = l >> 4;
  const int n0  = w * 32;
  const int wg  = blockIdx.x;

  bf16x8 Bf[8][2], Bg[8][2], Bx[4][2];
#pragma unroll
  for (int ks = 0; ks < 8; ++ks) {
#pragma unroll
    for (int nt = 0; nt < 2; ++nt) {
      const int n = n0 + nt * 16 + lr;
      const int k = ks * 32 + lg * 8;
      Bf[ks][nt] = loadw8(Wfh + n * HD + k);
      Bg[ks][nt] = loadw8(Wgh + n * HD + k);
    }
  }
  {
    bf16x8 z = (bf16x8)(short)0;
    const float* WxArr[3] = {Wfx, Wgx, Wox};
#pragma unroll
    for (int nt = 0; nt < 2; ++nt) {
      const int n = n0 + nt * 16 + lr;
#pragma unroll
      for (int g = 0; g < 3; ++g) {
        Bx[g][nt] = (lg == 0) ? loadw8(WxArr[g] + n * 8) : z;
      }
      Bx[3][nt] = (lg >= 1) ? loadw8(Wi + n * 24 + (lg - 1) * 8) : z;
    }
  }

  short* bo = Bo_sh + w * (16 * 512);
#pragma unroll
  for (int ks = 0; ks < 8; ++ks) {
#pragma unroll
    for (int nt = 0; nt < 2; ++nt) {
      const int n = n0 + nt * 16 + lr;
      bf16x8 fr = loadw8(Woh + n * HD + ks * 32 + lg * 8);
      *reinterpret_cast<bf16x8*>(bo + (ks * 2 + nt) * 512 + l * 8) = fr;
    }
  }

  float bias[4][2], woutv[2], cst[2];
#pragma unroll
  for (int nt = 0; nt < 2; ++nt) {
    const int n = n0 + nt * 16 + lr;
    bias[0][nt] = bfx[n] + bfh[n];
    bias[1][nt] = bgx[n] + bgh[n];
    bias[2][nt] = box_[n] + boh[n];
    bias[3][nt] = bi[n];
    woutv[nt] = Wout[n];
    cst[nt] = c0[n];
  }
  const float boutv = bout[0];

  for (int idx = tid; idx < 2 * FABUF; idx += 512) A_sh[idx] = 0;
  __syncthreads();
  for (int idx = tid; idx < 4 * 256; idx += 512) {
    A_sh[(4 * (idx >> 8)) * FASTR + (idx & 255)] = f2bf(h0[idx & 255]);
  }
  if (tid < 128) {
    const int row = tid >> 5, k = tid & 31;
    A_sh[(4 * row) * FASTR + 256 + k] = f2bf(x[((size_t)(wg * 4 + row) * T_LEN) * 32 + k]);
  }
  __syncthreads();

  const float* xp = x + (size_t)(wg * 4 + ((tid >> 5) & 3)) * T_LEN * 32 + (tid & 31);
  const int akoff = lg * 8;

  for (int t = 0; t < T_LEN; ++t) {
    const int cur = t & 1;
    const short* ArowC = A_sh + cur * FABUF + lr * FASTR;
    short* Anxt = A_sh + (cur ^ 1) * FABUF;

    if (t > 0 && w == 0 && l < 4) {
      float s = boutv;
#pragma unroll
      for (int ww = 0; ww < 8; ++ww) s += out_part[cur ^ 1][l][ww];
      out[(size_t)(wg * 4 + l) * T_LEN + (t - 1)] = s;
    }

    float xval = 0.0f;
    if (tid < 128) {
      const int tn = (t + 1 < T_LEN) ? (t + 1) : (T_LEN - 1);
      xval = xp[(size_t)tn * 32];
    }

    f32x4 acc[4][2];
#pragma unroll
    for (int g = 0; g < 4; ++g) {
#pragma unroll
      for (int nt = 0; nt < 2; ++nt) {
        f32x4 v; v[0] = bias[g][nt]; v[1] = bias[g][nt]; v[2] = bias[g][nt]; v[3] = bias[g][nt];
        acc[g][nt] = v;
      }
    }

#pragma unroll
    for (int ks = 0; ks < 8; ++ks) {
      const bf16x8 a = *reinterpret_cast<const bf16x8*>(ArowC + ks * 32 + akoff);
      acc[0][0] = __builtin_amdgcn_mfma_f32_16x16x32_bf16(a, Bf[ks][0], acc[0][0], 0, 0, 0);
      acc[0][1] = __builtin_amdgcn_mfma_f32_16x16x32_bf16(a, Bf[ks][1], acc[0][1], 0, 0, 0);
      acc[1][0] = __builtin_amdgcn_mfma_f32_16x16x32_bf16(a, Bg[ks][0], acc[1][0], 0, 0, 0);
      acc[1][1] = __builtin_amdgcn_mfma_f32_16x16x32_bf16(a, Bg[ks][1], acc[1][1], 0, 0, 0);
    }
    {
      const bf16x8 axv = *reinterpret_cast<const bf16x8*>(ArowC + 256 + akoff);
      acc[3][0] = __builtin_amdgcn_mfma_f32_16x16x32_bf16(axv, Bx[3][0], acc[3][0], 0, 0, 0);
      acc[3][1] = __builtin_amdgcn_mfma_f32_16x16x32_bf16(axv, Bx[3][1], acc[3][1], 0, 0, 0);
      acc[0][0] = __builtin_amdgcn_mfma_f32_16x16x32_bf16(axv, Bx[0][0], acc[0][0], 0, 0, 0);
      acc[0][1] = __builtin_amdgcn_mfma_f32_16x16x32_bf16(axv, Bx[0][1], acc[0][1], 0, 0, 0);
      acc[1][0] = __builtin_amdgcn_mfma_f32_16x16x32_bf16(axv, Bx[1][0], acc[1][0], 0, 0, 0);
      acc[1][1] = __builtin_amdgcn_mfma_f32_16x16x32_bf16(axv, Bx[1][1], acc[1][1], 0, 0, 0);
      acc[2][0] = __builtin_amdgcn_mfma_f32_16x16x32_bf16(axv, Bx[2][0], acc[2][0], 0, 0, 0);
      acc[2][1] = __builtin_amdgcn_mfma_f32_16x16x32_bf16(axv, Bx[2][1], acc[2][1], 0, 0, 0);
    }
#pragma unroll
    for (int ks = 0; ks < 8; ++ks) {
      const bf16x8 a  = *reinterpret_cast<const bf16x8*>(ArowC + ks * 32 + akoff);
      const bf16x8 b0 = *reinterpret_cast<const bf16x8*>(bo + (ks * 2 + 0) * 512 + l * 8);
      const bf16x8 b1 = *reinterpret_cast<const bf16x8*>(bo + (ks * 2 + 1) * 512 + l * 8);
      acc[2][0] = __builtin_amdgcn_mfma_f32_16x16x32_bf16(a, b0, acc[2][0], 0, 0, 0);
      acc[2][1] = __builtin_amdgcn_mfma_f32_16x16x32_bf16(a, b1, acc[2][1], 0, 0, 0);
    }

    float tcv[2];
#pragma unroll
    for (int nt = 0; nt < 2; ++nt) {
      const float sf = sigm(acc[0][nt][0]);
      const float tg = tanh_(acc[1][nt][0]);
      const float si = sigm(acc[3][nt][0]);
      const float c  = sf * cst[nt] + si * tg;
      cst[nt] = c;
      tcv[nt] = tanh_(c);
    }

    float po = 0.0f;
    short hpk[2];
#pragma unroll
    for (int nt = 0; nt < 2; ++nt) {
      const float so = sigm(acc[2][nt][0]);
      const float hv = so * tcv[nt];
      hpk[nt] = f2bf(hv);
      po += so * woutv[nt];
    }

    Anxt[(4 * lg) * FASTR + (n0 + lr)]      = hpk[0];
    Anxt[(4 * lg) * FASTR + (n0 + 16 + lr)] = hpk[1];
    if (tid < 128) Anxt[(4 * (tid >> 5)) * FASTR + 256 + (tid & 31)] = f2bf(xval);

#pragma unroll
    for (int mk = 1; mk < 16; mk <<= 1) {
      po += __shfl_xor(po, mk, 64);
    }
    if (lr == 0) out_part[cur][lg][w] = po;

    __syncthreads();
  }

  if (w == 0 && l < 4) {
    float s = boutv;
#pragma unroll
    for (int ww = 0; ww < 8; ++ww) s += out_part[(T_LEN - 1) & 1][l][ww];
    out[(size_t)(wg * 4 + l) * T_LEN + (T_LEN - 1)] = s;
  }
}

extern "C" void kernel_launch(void* const* d_in, const int* in_sizes, int n_in,
                              void* d_out, int out_size, void* d_ws, size_t ws_size,
                              hipStream_t stream) {
  const float* x    = (const float*)d_in[0];
  const float* c0   = (const float*)d_in[1];
  const float* h0   = (const float*)d_in[2];
  const float* Wi   = (const float*)d_in[3];
  const float* bi   = (const float*)d_in[4];
  const float* Wfx  = (const float*)d_in[5];
  const float* bfx  = (const float*)d_in[6];
  const float* Wfh  = (const float*)d_in[7];
  const float* bfh  = (const float*)d_in[8];
  const float* Wgx  = (const float*)d_in[9];
  const float* bgx  = (const float*)d_in[10];
  const float* Wgh  = (const float*)d_in[11];
  const float* bgh  = (const float*)d_in[12];
  const float* Wox  = (const float*)d_in[13];
  const float* box_ = (const float*)d_in[14];
  const float* Woh  = (const float*)d_in[15];
  const float* boh  = (const float*)d_in[16];
  const float* Wout = (const float*)d_in[17];
  const float* bout = (const float*)d_in[18];

  // ws layout: hs bf16[128*256] @0 (64K); cs f32[128*256] @64K (128K); P @256K.
  const size_t perT = (size_t)128 * 1024 * sizeof(unsigned short);  // 256 KiB per timestep
  const size_t pOff = 262144;

  int TC = 0;
  for (int cand = T_LEN; cand >= 128; cand >>= 1) {
    if (ws_size >= pOff + (size_t)cand * perT) { TC = cand; break; }
  }

  if (TC) {
    unsigned short* hs = (unsigned short*)d_ws;
    float*          cs = (float*)((char*)d_ws + 65536);
    unsigned short* P  = (unsigned short*)((char*)d_ws + pOff);
    for (int t0 = 0; t0 < T_LEN; t0 += TC) {
      precomp_kernel<<<dim3(128, TC / 128), dim3(256), 0, stream>>>(
          x, Wi, bi, Wfx, bfx, bfh, Wgx, bgx, bgh, Wox, box_, boh, P, t0, TC);
      ealstm_rec<<<dim3(32), dim3(256), 0, stream>>>(
          P, c0, h0, hs, cs, Wfh, Wgh, Woh, Wout, bout,
          (float*)d_out, t0, TC, (t0 == 0) ? 1 : 0);
    }
  } else {
    ealstm_fallback<<<dim3(32), dim3(512), 0, stream>>>(
        x, c0, h0, Wi, bi, Wfx, bfx, Wfh, bfh,
        Wgx, bgx, Wgh, bgh, Wox, box_, Woh, boh, Wout, bout,
        (float*)d_out);
  }
}

// Round 9
// 4435.071 us; speedup vs baseline: 1.0637x; 1.0637x over previous
//
#include <hip/hip_runtime.h>
#include <hip/hip_bf16.h>

// EA-LSTM for MI355X (gfx950), round 9: chunked two-phase, all-register weights.
// ws layout: [0,64K) h-state bf16[128][256]; [64K,192K) c-state f32[128][256];
//            [256K, 256K + TC*256K) P chunk buffer.
// precomp: P[b][tloc][pos=w*16+lr][16 shorts: f*4,g*4,o*4,i*4] (nt=0..3 each);
//   f,g,o are x-projection+biases (bf16), i is sigm(i-pre).
// rec: 32 WGs x 256 thr (4 waves, 1 wave/SIMD, 512-reg budget incl. AGPRs).
//   Wave w owns ch [w*64,(w+1)*64); batch row b staged at A-row 4b so MFMA D
//   r==0 gives one gate-set per (lane,nt). ALL recurrent weights (f,g,o x 8
//   K-steps x 4 nt = 384 regs) live in the unified VGPR/AGPR file -> the only
//   LDS traffic is 8 A-frag reads/wave/step. P read as 2x16B/lane, prefetched
//   2 steps ahead. Fallback (tiny ws): round-6 kernel (4060 us).

#define T_LEN 2048
#define HD 256

typedef __attribute__((ext_vector_type(8))) short bf16x8;
typedef __attribute__((ext_vector_type(4))) float f32x4;
typedef __attribute__((ext_vector_type(4))) unsigned int u32x4;

#define LOG2E 1.4426950408889634f

__device__ __forceinline__ short f2bf(float f) {
  unsigned u = __float_as_uint(f);
  unsigned r = (u + 0x7fffu + ((u >> 16) & 1u)) >> 16;
  return (short)r;
}

__device__ __forceinline__ bf16x8 loadw8(const float* p) {
  bf16x8 r;
#pragma unroll
  for (int i = 0; i < 8; ++i) r[i] = f2bf(p[i]);
  return r;
}

__device__ __forceinline__ float sigm(float x) {
  float e = __builtin_amdgcn_exp2f(-LOG2E * x);
  return __builtin_amdgcn_rcpf(1.0f + e);
}

// clamp-free tanh: 1 - 2/(e^{2x}+1); saturates to +/-1, NaN-free.
__device__ __forceinline__ float tanh_(float x) {
  float e = __builtin_amdgcn_exp2f((2.0f * LOG2E) * x);
  return 1.0f - 2.0f * __builtin_amdgcn_rcpf(e + 1.0f);
}

// bf16 short idx (0..7) out of a 16B packed block
__device__ __forceinline__ float punp16(u32x4 p, int idx) {
  unsigned d = p[idx >> 1];
  return __uint_as_float((idx & 1) ? (d & 0xffff0000u) : (d << 16));
}

// ============================ phase 1: precompute ============================
__global__ __launch_bounds__(256) void precomp_kernel(
    const float* __restrict__ x,
    const float* __restrict__ Wi,  const float* __restrict__ bi,
    const float* __restrict__ Wfx, const float* __restrict__ bfx, const float* __restrict__ bfh,
    const float* __restrict__ Wgx, const float* __restrict__ bgx, const float* __restrict__ bgh,
    const float* __restrict__ Wox, const float* __restrict__ box_, const float* __restrict__ boh,
    unsigned short* __restrict__ P, int t0, int tlen)
{
  const int tid = threadIdx.x;
  const int b   = blockIdx.x;       // 0..127
  const int w   = tid >> 6;
  const int lr  = (tid >> 2) & 15;
  const int nt  = tid & 3;
  const int ch  = w * 64 + nt * 16 + lr;

  float wf[8], wg[8], wo[8], wi24[24];
#pragma unroll
  for (int d = 0; d < 8; ++d) {
    wf[d] = Wfx[ch * 8 + d];
    wg[d] = Wgx[ch * 8 + d];
    wo[d] = Wox[ch * 8 + d];
  }
#pragma unroll
  for (int d = 0; d < 24; ++d) wi24[d] = Wi[ch * 24 + d];
  const float cf = bfx[ch] + bfh[ch];
  const float cg = bgx[ch] + bgh[ch];
  const float co = box_[ch] + boh[ch];
  const float ci = bi[ch];

  const int tb = t0 + blockIdx.y * 128;
  const float* xb = x + ((size_t)b * T_LEN + tb) * 32;
  unsigned short* Pb = P + ((size_t)b * tlen + (tb - t0)) * 1024 + (w * 16 + lr) * 16 + nt;

  for (int ti = 0; ti < 128; ++ti) {
    const float* xr = xb + (size_t)ti * 32;
    float fv = cf, gv = cg, ov = co, iv = ci;
#pragma unroll
    for (int d = 0; d < 8; ++d) {
      const float xv = xr[d];
      fv += xv * wf[d];
      gv += xv * wg[d];
      ov += xv * wo[d];
    }
#pragma unroll
    for (int d = 0; d < 24; ++d) iv += xr[8 + d] * wi24[d];
    iv = sigm(iv);
    unsigned short* Pp = Pb + (size_t)ti * 1024;
    Pp[0]  = (unsigned short)f2bf(fv);
    Pp[4]  = (unsigned short)f2bf(gv);
    Pp[8]  = (unsigned short)f2bf(ov);
    Pp[12] = (unsigned short)f2bf(iv);
  }
}

// ============================ phase 2: recurrence ============================
// A tile: 16 rows x 264 cols bf16 (h only). Valid rows at {0,4,8,12}.
#define ASTR 264
#define ABUF (16 * ASTR)

__global__ __launch_bounds__(256, 1) void ealstm_rec(
    const unsigned short* __restrict__ P,
    const float* __restrict__ c0, const float* __restrict__ h0,
    unsigned short* __restrict__ hs, float* __restrict__ cs,
    const float* __restrict__ Wfh, const float* __restrict__ Wgh, const float* __restrict__ Woh,
    const float* __restrict__ Wout, const float* __restrict__ bout,
    float* __restrict__ out, int t0, int tlen, int first)
{
  __shared__ __attribute__((aligned(16))) short A_sh[2 * ABUF];  // 16896 B
  __shared__ float out_part[2][4][4];                            // 128 B

  const int tid = threadIdx.x;
  const int w   = tid >> 6;   // wave 0..3, owns ch [w*64, w*64+64)
  const int l   = tid & 63;
  const int lr  = l & 15;
  const int lg  = l >> 4;     // activation row = lg (A-row trick)
  const int wg  = blockIdx.x; // 4-row batch block

  // ---- ALL recurrent weights in registers (VGPR+AGPR unified file) ----
  bf16x8 Bf[8][4], Bg[8][4], Bo[8][4];
#pragma unroll
  for (int ks = 0; ks < 8; ++ks) {
#pragma unroll
    for (int nt = 0; nt < 4; ++nt) {
      const int n = w * 64 + nt * 16 + lr;
      const int k = ks * 32 + lg * 8;
      Bf[ks][nt] = loadw8(Wfh + n * HD + k);
      Bg[ks][nt] = loadw8(Wgh + n * HD + k);
      Bo[ks][nt] = loadw8(Woh + n * HD + k);
    }
  }

  // ---- Wout, c-state ----
  float woutv[4], cst[4];
#pragma unroll
  for (int nt = 0; nt < 4; ++nt) {
    const int n = w * 64 + nt * 16 + lr;
    woutv[nt] = Wout[n];
    cst[nt]   = first ? c0[n] : cs[(size_t)(wg * 4 + lg) * 256 + n];
  }
  const float boutv = bout[0];

  // ---- zero both A buffers; stage h-state at A-rows {0,4,8,12} ----
  for (int idx = tid; idx < 2 * ABUF; idx += 256) A_sh[idx] = 0;
  __syncthreads();
  for (int idx = tid; idx < 4 * 256; idx += 256) {
    const int row = idx >> 8, col = idx & 255;
    const short hv = first ? f2bf(h0[col])
                           : (short)hs[(size_t)(wg * 4 + row) * 256 + col];
    A_sh[(4 * row) * ASTR + col] = hv;
  }
  __syncthreads();

  // per-lane P base: row = wg*4+lg, pos = w*16+lr, 16 shorts each, stride 1024/t
  const unsigned short* Pb = P + ((size_t)(wg * 4 + lg) * tlen) * 1024 + (w * 16 + lr) * 16;
  const int akoff = lg * 8;

  // 2-deep P prefetch: pX0 = data(t), pX1 = data(t+1), pX2 = in flight (t+2)
  u32x4 pA0, pB0, pA1, pB1, pA2, pB2;
  pA0 = *reinterpret_cast<const u32x4*>(Pb);
  pB0 = *reinterpret_cast<const u32x4*>(Pb + 8);
  {
    const unsigned short* p1 = Pb + ((tlen > 1) ? 1024 : 0);
    pA1 = *reinterpret_cast<const u32x4*>(p1);
    pB1 = *reinterpret_cast<const u32x4*>(p1 + 8);
  }

  const f32x4 z4 = {0.f, 0.f, 0.f, 0.f};

#pragma unroll 2
  for (int t = 0; t < tlen; ++t) {
    const int cur = t & 1;
    const short* ArowC = A_sh + cur * ABUF + lr * ASTR;
    short* Anxt = A_sh + (cur ^ 1) * ABUF;

    // issue prefetch for t+2 (clamped)
    {
      const int tn = (t + 2 < tlen) ? (t + 2) : (tlen - 1);
      const unsigned short* p2 = Pb + (size_t)tn * 1024;
      pA2 = *reinterpret_cast<const u32x4*>(p2);
      pB2 = *reinterpret_cast<const u32x4*>(p2 + 8);
    }

    // finalize previous step's output (hidden under this step's MFMA phase)
    if (t > 0 && w == 0 && l < 4) {
      float s = boutv;
#pragma unroll
      for (int ww = 0; ww < 4; ++ww) s += out_part[cur ^ 1][l][ww];
      out[(size_t)(wg * 4 + l) * T_LEN + (t0 + t - 1)] = s;
    }

    // ---- K-loop: 1 A-read -> 12 MFMAs; ks=0 folds the acc zero-init ----
    f32x4 acc[3][4];
    {
      const bf16x8 a = *reinterpret_cast<const bf16x8*>(ArowC + akoff);
#pragma unroll
      for (int nt = 0; nt < 4; ++nt)
        acc[0][nt] = __builtin_amdgcn_mfma_f32_16x16x32_bf16(a, Bf[0][nt], z4, 0, 0, 0);
#pragma unroll
      for (int nt = 0; nt < 4; ++nt)
        acc[1][nt] = __builtin_amdgcn_mfma_f32_16x16x32_bf16(a, Bg[0][nt], z4, 0, 0, 0);
#pragma unroll
      for (int nt = 0; nt < 4; ++nt)
        acc[2][nt] = __builtin_amdgcn_mfma_f32_16x16x32_bf16(a, Bo[0][nt], z4, 0, 0, 0);
    }
#pragma unroll
    for (int ks = 1; ks < 8; ++ks) {
      const bf16x8 a = *reinterpret_cast<const bf16x8*>(ArowC + ks * 32 + akoff);
#pragma unroll
      for (int nt = 0; nt < 4; ++nt)
        acc[0][nt] = __builtin_amdgcn_mfma_f32_16x16x32_bf16(a, Bf[ks][nt], acc[0][nt], 0, 0, 0);
#pragma unroll
      for (int nt = 0; nt < 4; ++nt)
        acc[1][nt] = __builtin_amdgcn_mfma_f32_16x16x32_bf16(a, Bg[ks][nt], acc[1][nt], 0, 0, 0);
#pragma unroll
      for (int nt = 0; nt < 4; ++nt)
        acc[2][nt] = __builtin_amdgcn_mfma_f32_16x16x32_bf16(a, Bo[ks][nt], acc[2][nt], 0, 0, 0);
    }

    // ---- activations: 4 gate-sets per lane (row = lg, ch = w*64 + nt*16 + lr) ----
    float po = 0.0f;
#pragma unroll
    for (int nt = 0; nt < 4; ++nt) {
      const float fpre = acc[0][nt][0] + punp16(pA0, 0 + nt);
      const float gpre = acc[1][nt][0] + punp16(pA0, 4 + nt);
      const float opre = acc[2][nt][0] + punp16(pB0, 0 + nt);
      const float iv   = punp16(pB0, 4 + nt);  // sigmoid already applied
      const float sf = sigm(fpre);
      const float tg = tanh_(gpre);
      const float so = sigm(opre);
      const float c  = sf * cst[nt] + iv * tg;
      cst[nt] = c;
      const float hv = so * tanh_(c);
      Anxt[(4 * lg) * ASTR + (w * 64 + nt * 16 + lr)] = f2bf(hv);
      po += so * woutv[nt];
    }

    // po reduce over the 16 lr-lanes -> (row = lg, wave w)
#pragma unroll
    for (int mk = 1; mk < 16; mk <<= 1) {
      po += __shfl_xor(po, mk, 64);
    }
    if (lr == 0) out_part[cur][lg][w] = po;

    // roll P prefetch buffers
    pA0 = pA1; pB0 = pB1;
    pA1 = pA2; pB1 = pB2;

    __syncthreads();  // single per-step barrier
  }

  // final output of the chunk
  if (w == 0 && l < 4) {
    float s = boutv;
#pragma unroll
    for (int ww = 0; ww < 4; ++ww) s += out_part[(tlen - 1) & 1][l][ww];
    out[(size_t)(wg * 4 + l) * T_LEN + (t0 + tlen - 1)] = s;
  }

  // ---- persist c/h state for the next chunk ----
  {
    const short* Afin = A_sh + (tlen & 1) * ABUF;
#pragma unroll
    for (int nt = 0; nt < 4; ++nt) {
      const int n = w * 64 + nt * 16 + lr;
      hs[(size_t)(wg * 4 + lg) * 256 + n] = (unsigned short)Afin[(4 * lg) * ASTR + n];
      cs[(size_t)(wg * 4 + lg) * 256 + n] = cst[nt];
    }
  }
}

// ============================ fallback: round-6 kernel ============================
#define FASTR 296
#define FABUF (16 * FASTR)

__global__ __launch_bounds__(512, 2) void ealstm_fallback(
    const float* __restrict__ x, const float* __restrict__ c0, const float* __restrict__ h0,
    const float* __restrict__ Wi, const float* __restrict__ bi,
    const float* __restrict__ Wfx, const float* __restrict__ bfx,
    const float* __restrict__ Wfh, const float* __restrict__ bfh,
    const float* __restrict__ Wgx, const float* __restrict__ bgx,
    const float* __restrict__ Wgh, const float* __restrict__ bgh,
    const float* __restrict__ Wox, const float* __restrict__ box_,
    const float* __restrict__ Woh, const float* __restrict__ boh,
    const float* __restrict__ Wout, const float* __restrict__ bout,
    float* __restrict__ out)
{
  __shared__ __attribute__((aligned(16))) short A_sh[2 * FABUF];
  __shared__ __attribute__((aligned(16))) short Bo_sh[8 * 16 * 512];
  __shared__ float out_part[2][4][8];

  const int tid = threadIdx.x;
  const int w   = tid >> 6;
  const int l   = tid & 63;
  const int lr  = l & 15;
  const int lg  = l >> 4;
  const int n0  = w * 32;
  const int wg  = blockIdx.x;

  bf16x8 Bf[8][2], Bg[8][2], Bx[4][2];
#pragma unroll
  for (int ks = 0; ks < 8; ++ks) {
#pragma unroll
    for (int nt = 0; nt < 2; ++nt) {
      const int n = n0 + nt * 16 + lr;
      const int k = ks * 32 + lg * 8;
      Bf[ks][nt] = loadw8(Wfh + n * HD + k);
      Bg[ks][nt] = loadw8(Wgh + n * HD + k);
    }
  }
  {
    bf16x8 z = (bf16x8)(short)0;
    const float* WxArr[3] = {Wfx, Wgx, Wox};
#pragma unroll
    for (int nt = 0; nt < 2; ++nt) {
      const int n = n0 + nt * 16 + lr;
#pragma unroll
      for (int g = 0; g < 3; ++g) {
        Bx[g][nt] = (lg == 0) ? loadw8(WxArr[g] + n * 8) : z;
      }
      Bx[3][nt] = (lg >= 1) ? loadw8(Wi + n * 24 + (lg - 1) * 8) : z;
    }
  }

  short* bo = Bo_sh + w * (16 * 512);
#pragma unroll
  for (int ks = 0; ks < 8; ++ks) {
#pragma unroll
    for (int nt = 0; nt < 2; ++nt) {
      const int n = n0 + nt * 16 + lr;
      bf16x8 fr = loadw8(Woh + n * HD + ks * 32 + lg * 8);
      *reinterpret_cast<bf16x8*>(bo + (ks * 2 + nt) * 512 + l * 8) = fr;
    }
  }

  float bias[4][2], woutv[2], cst[2];
#pragma unroll
  for (int nt = 0; nt < 2; ++nt) {
    const int n = n0 + nt * 16 + lr;
    bias[0][nt] = bfx[n] + bfh[n];
    bias[1][nt] = bgx[n] + bgh[n];
    bias[2][nt] = box_[n] + boh[n];
    bias[3][nt] = bi[n];
    woutv[nt] = Wout[n];
    cst[nt] = c0[n];
  }
  const float boutv = bout[0];

  for (int idx = tid; idx < 2 * FABUF; idx += 512) A_sh[idx] = 0;
  __syncthreads();
  for (int idx = tid; idx < 4 * 256; idx += 512) {
    A_sh[(4 * (idx >> 8)) * FASTR + (idx & 255)] = f2bf(h0[idx & 255]);
  }
  if (tid < 128) {
    const int row = tid >> 5, k = tid & 31;
    A_sh[(4 * row) * FASTR + 256 + k] = f2bf(x[((size_t)(wg * 4 + row) * T_LEN) * 32 + k]);
  }
  __syncthreads();

  const float* xp = x + (size_t)(wg * 4 + ((tid >> 5) & 3)) * T_LEN * 32 + (tid & 31);
  const int akoff = lg * 8;

  for (int t = 0; t < T_LEN; ++t) {
    const int cur = t & 1;
    const short* ArowC = A_sh + cur * FABUF + lr * FASTR;
    short* Anxt = A_sh + (cur ^ 1) * FABUF;

    if (t > 0 && w == 0 && l < 4) {
      float s = boutv;
#pragma unroll
      for (int ww = 0; ww < 8; ++ww) s += out_part[cur ^ 1][l][ww];
      out[(size_t)(wg * 4 + l) * T_LEN + (t - 1)] = s;
    }

    float xval = 0.0f;
    if (tid < 128) {
      const int tn = (t + 1 < T_LEN) ? (t + 1) : (T_LEN - 1);
      xval = xp[(size_t)tn * 32];
    }

    f32x4 acc[4][2];
#pragma unroll
    for (int g = 0; g < 4; ++g) {
#pragma unroll
      for (int nt = 0; nt < 2; ++nt) {
        f32x4 v; v[0] = bias[g][nt]; v[1] = bias[g][nt]; v[2] = bias[g][nt]; v[3] = bias[g][nt];
        acc[g][nt] = v;
      }
    }

#pragma unroll
    for (int ks = 0; ks < 8; ++ks) {
      const bf16x8 a = *reinterpret_cast<const bf16x8*>(ArowC + ks * 32 + akoff);
      acc[0][0] = __builtin_amdgcn_mfma_f32_16x16x32_bf16(a, Bf[ks][0], acc[0][0], 0, 0, 0);
      acc[0][1] = __builtin_amdgcn_mfma_f32_16x16x32_bf16(a, Bf[ks][1], acc[0][1], 0, 0, 0);
      acc[1][0] = __builtin_amdgcn_mfma_f32_16x16x32_bf16(a, Bg[ks][0], acc[1][0], 0, 0, 0);
      acc[1][1] = __builtin_amdgcn_mfma_f32_16x16x32_bf16(a, Bg[ks][1], acc[1][1], 0, 0, 0);
    }
    {
      const bf16x8 axv = *reinterpret_cast<const bf16x8*>(ArowC + 256 + akoff);
      acc[3][0] = __builtin_amdgcn_mfma_f32_16x16x32_bf16(axv, Bx[3][0], acc[3][0], 0, 0, 0);
      acc[3][1] = __builtin_amdgcn_mfma_f32_16x16x32_bf16(axv, Bx[3][1], acc[3][1], 0, 0, 0);
      acc[0][0] = __builtin_amdgcn_mfma_f32_16x16x32_bf16(axv, Bx[0][0], acc[0][0], 0, 0, 0);
      acc[0][1] = __builtin_amdgcn_mfma_f32_16x16x32_bf16(axv, Bx[0][1], acc[0][1], 0, 0, 0);
      acc[1][0] = __builtin_amdgcn_mfma_f32_16x16x32_bf16(axv, Bx[1][0], acc[1][0], 0, 0, 0);
      acc[1][1] = __builtin_amdgcn_mfma_f32_16x16x32_bf16(axv, Bx[1][1], acc[1][1], 0, 0, 0);
      acc[2][0] = __builtin_amdgcn_mfma_f32_16x16x32_bf16(axv, Bx[2][0], acc[2][0], 0, 0, 0);
      acc[2][1] = __builtin_amdgcn_mfma_f32_16x16x32_bf16(axv, Bx[2][1], acc[2][1], 0, 0, 0);
    }
#pragma unroll
    for (int ks = 0; ks < 8; ++ks) {
      const bf16x8 a  = *reinterpret_cast<const bf16x8*>(ArowC + ks * 32 + akoff);
      const bf16x8 b0 = *reinterpret_cast<const bf16x8*>(bo + (ks * 2 + 0) * 512 + l * 8);
      const bf16x8 b1 = *reinterpret_cast<const bf16x8*>(bo + (ks * 2 + 1) * 512 + l * 8);
      acc[2][0] = __builtin_amdgcn_mfma_f32_16x16x32_bf16(a, b0, acc[2][0], 0, 0, 0);
      acc[2][1] = __builtin_amdgcn_mfma_f32_16x16x32_bf16(a, b1, acc[2][1], 0, 0, 0);
    }

    float tcv[2];
#pragma unroll
    for (int nt = 0; nt < 2; ++nt) {
      const float sf = sigm(acc[0][nt][0]);
      const float tg = tanh_(acc[1][nt][0]);
      const float si = sigm(acc[3][nt][0]);
      const float c  = sf * cst[nt] + si * tg;
      cst[nt] = c;
      tcv[nt] = tanh_(c);
    }

    float po = 0.0f;
    short hpk[2];
#pragma unroll
    for (int nt = 0; nt < 2; ++nt) {
      const float so = sigm(acc[2][nt][0]);
      const float hv = so * tcv[nt];
      hpk[nt] = f2bf(hv);
      po += so * woutv[nt];
    }

    Anxt[(4 * lg) * FASTR + (n0 + lr)]      = hpk[0];
    Anxt[(4 * lg) * FASTR + (n0 + 16 + lr)] = hpk[1];
    if (tid < 128) Anxt[(4 * (tid >> 5)) * FASTR + 256 + (tid & 31)] = f2bf(xval);

#pragma unroll
    for (int mk = 1; mk < 16; mk <<= 1) {
      po += __shfl_xor(po, mk, 64);
    }
    if (lr == 0) out_part[cur][lg][w] = po;

    __syncthreads();
  }

  if (w == 0 && l < 4) {
    float s = boutv;
#pragma unroll
    for (int ww = 0; ww < 8; ++ww) s += out_part[(T_LEN - 1) & 1][l][ww];
    out[(size_t)(wg * 4 + l) * T_LEN + (T_LEN - 1)] = s;
  }
}

extern "C" void kernel_launch(void* const* d_in, const int* in_sizes, int n_in,
                              void* d_out, int out_size, void* d_ws, size_t ws_size,
                              hipStream_t stream) {
  const float* x    = (const float*)d_in[0];
  const float* c0   = (const float*)d_in[1];
  const float* h0   = (const float*)d_in[2];
  const float* Wi   = (const float*)d_in[3];
  const float* bi   = (const float*)d_in[4];
  const float* Wfx  = (const float*)d_in[5];
  const float* bfx  = (const float*)d_in[6];
  const float* Wfh  = (const float*)d_in[7];
  const float* bfh  = (const float*)d_in[8];
  const float* Wgx  = (const float*)d_in[9];
  const float* bgx  = (const float*)d_in[10];
  const float* Wgh  = (const float*)d_in[11];
  const float* bgh  = (const float*)d_in[12];
  const float* Wox  = (const float*)d_in[13];
  const float* box_ = (const float*)d_in[14];
  const float* Woh  = (const float*)d_in[15];
  const float* boh  = (const float*)d_in[16];
  const float* Wout = (const float*)d_in[17];
  const float* bout = (const float*)d_in[18];

  // ws layout: hs bf16[128*256] @0 (64K); cs f32[128*256] @64K (128K); P @256K.
  const size_t perT = (size_t)128 * 1024 * sizeof(unsigned short);  // 256 KiB per timestep
  const size_t pOff = 262144;

  int TC = 0;
  for (int cand = T_LEN; cand >= 128; cand >>= 1) {
    if (ws_size >= pOff + (size_t)cand * perT) { TC = cand; break; }
  }

  if (TC) {
    unsigned short* hs = (unsigned short*)d_ws;
    float*          cs = (float*)((char*)d_ws + 65536);
    unsigned short* P  = (unsigned short*)((char*)d_ws + pOff);
    for (int t0 = 0; t0 < T_LEN; t0 += TC) {
      precomp_kernel<<<dim3(128, TC / 128), dim3(256), 0, stream>>>(
          x, Wi, bi, Wfx, bfx, bfh, Wgx, bgx, bgh, Wox, box_, boh, P, t0, TC);
      ealstm_rec<<<dim3(32), dim3(256), 0, stream>>>(
          P, c0, h0, hs, cs, Wfh, Wgh, Woh, Wout, bout,
          (float*)d_out, t0, TC, (t0 == 0) ? 1 : 0);
    }
  } else {
    ealstm_fallback<<<dim3(32), dim3(512), 0, stream>>>(
        x, c0, h0, Wi, bi, Wfx, bfx, Wfh, bfh,
        Wgx, bgx, Wgh, bgh, Wox, box_, Woh, boh, Wout, bout,
        (float*)d_out);
  }
}

// Round 10
// 4333.134 us; speedup vs baseline: 1.0887x; 1.0235x over previous
//
#include <hip/hip_runtime.h>
#include <hip/hip_bf16.h>

// EA-LSTM for MI355X (gfx950), round 10: chunked two-phase.
// Change vs R9: precomp rewritten as an MFMA GEMM ([B*T,32] x [32,1024]) --
// write-bound ~60-120us/chunk instead of ~1100us. rec kernel is UNCHANGED.
// ws layout: [0,64K) h-state bf16[128][256]; [64K,192K) c-state f32[128][256];
//            [256K, 256K + TC*256K) P chunk buffer.
// P[b][tloc][pos=w*16+lr][16 shorts: f*4,g*4,o*4,i*4] (nt=0..3 each);
//   f,g,o = x-projection+biases (bf16); i = sigm(i-pre).

#define T_LEN 2048
#define HD 256

typedef __attribute__((ext_vector_type(8))) short bf16x8;
typedef __attribute__((ext_vector_type(4))) float f32x4;
typedef __attribute__((ext_vector_type(4))) unsigned int u32x4;

#define LOG2E 1.4426950408889634f

__device__ __forceinline__ short f2bf(float f) {
  unsigned u = __float_as_uint(f);
  unsigned r = (u + 0x7fffu + ((u >> 16) & 1u)) >> 16;
  return (short)r;
}

__device__ __forceinline__ bf16x8 loadw8(const float* p) {
  bf16x8 r;
#pragma unroll
  for (int i = 0; i < 8; ++i) r[i] = f2bf(p[i]);
  return r;
}

__device__ __forceinline__ float sigm(float x) {
  float e = __builtin_amdgcn_exp2f(-LOG2E * x);
  return __builtin_amdgcn_rcpf(1.0f + e);
}

// clamp-free tanh: 1 - 2/(e^{2x}+1); saturates to +/-1, NaN-free.
__device__ __forceinline__ float tanh_(float x) {
  float e = __builtin_amdgcn_exp2f((2.0f * LOG2E) * x);
  return 1.0f - 2.0f * __builtin_amdgcn_rcpf(e + 1.0f);
}

// bf16 short idx (0..7) out of a 16B packed block
__device__ __forceinline__ float punp16(u32x4 p, int idx) {
  unsigned d = p[idx >> 1];
  return __uint_as_float((idx & 1) ? (d & 0xffff0000u) : (d << 16));
}

// ===================== phase 1: precompute (MFMA GEMM) ======================
// A tile (M=16 t's, K=32): cols 0..7 = xd, 8..31 = xs.
// B frags: Wcat[g][ch][k]: g in {f,g,o}: k<8 -> Wgx[ch][k], else 0;
//          g = i: k>=8 -> Wi[ch][k-8], else 0. Bias folded into acc init.
// D: row = t-local = lg*4+r, col = ch = w*64 + nt*16 + lr.
__global__ __launch_bounds__(256) void precomp_mfma(
    const float* __restrict__ x,
    const float* __restrict__ Wi,  const float* __restrict__ bi,
    const float* __restrict__ Wfx, const float* __restrict__ bfx, const float* __restrict__ bfh,
    const float* __restrict__ Wgx, const float* __restrict__ bgx, const float* __restrict__ bgh,
    const float* __restrict__ Wox, const float* __restrict__ box_, const float* __restrict__ boh,
    unsigned short* __restrict__ P, int t0, int tlen)
{
  const int tid = threadIdx.x;
  const int w   = tid >> 6;   // wave -> ch slice [w*64, w*64+64)
  const int l   = tid & 63;
  const int lr  = l & 15;
  const int lg  = l >> 4;
  const int b   = blockIdx.x;                 // batch row
  const int tbase = t0 + blockIdx.y * 128;    // this block: 8 tiles of 16 t

  // ---- B-frags (Wcat) + biases, loaded once per block ----
  bf16x8 Bw[4][4];
  float bias[4][4];
  {
    bf16x8 z = (bf16x8)(short)0;
    const float* WxArr[3] = {Wfx, Wgx, Wox};
#pragma unroll
    for (int nt = 0; nt < 4; ++nt) {
      const int ch = w * 64 + nt * 16 + lr;
#pragma unroll
      for (int g = 0; g < 3; ++g) {
        Bw[g][nt] = (lg == 0) ? loadw8(WxArr[g] + ch * 8) : z;
      }
      Bw[3][nt] = (lg >= 1) ? loadw8(Wi + ch * 24 + (lg - 1) * 8) : z;
      bias[0][nt] = bfx[ch] + bfh[ch];
      bias[1][nt] = bgx[ch] + bgh[ch];
      bias[2][nt] = box_[ch] + boh[ch];
      bias[3][nt] = bi[ch];
    }
  }

#pragma unroll 1
  for (int tt = 0; tt < 8; ++tt) {
    const int trow = tbase + tt * 16;
    // A-frag: lane holds x[b][trow+lr][lg*8 .. lg*8+8)
    const bf16x8 a = loadw8(x + ((size_t)b * T_LEN + (trow + lr)) * 32 + lg * 8);

    f32x4 acc[4][4];
#pragma unroll
    for (int g = 0; g < 4; ++g) {
#pragma unroll
      for (int nt = 0; nt < 4; ++nt) {
        f32x4 v; v[0] = bias[g][nt]; v[1] = bias[g][nt]; v[2] = bias[g][nt]; v[3] = bias[g][nt];
        acc[g][nt] = __builtin_amdgcn_mfma_f32_16x16x32_bf16(a, Bw[g][nt], v, 0, 0, 0);
      }
    }

    // epilogue: per r, pack 16 shorts [f0..f3,g0..g3,o0..o3,i0..i3] and store 2x16B
#pragma unroll
    for (int r = 0; r < 4; ++r) {
      const int tl = (trow - t0) + lg * 4 + r;
      unsigned short* Pp = P + ((size_t)b * tlen + tl) * 1024 + (w * 16 + lr) * 16;
      bf16x8 lo, hi;
#pragma unroll
      for (int nt = 0; nt < 4; ++nt) {
        lo[0 + nt] = f2bf(acc[0][nt][r]);          // f
        lo[4 + nt] = f2bf(acc[1][nt][r]);          // g
        hi[0 + nt] = f2bf(acc[2][nt][r]);          // o
        hi[4 + nt] = f2bf(sigm(acc[3][nt][r]));    // i (sigmoid applied)
      }
      *reinterpret_cast<bf16x8*>(Pp)     = lo;
      *reinterpret_cast<bf16x8*>(Pp + 8) = hi;
    }
  }
}

// ============================ phase 2: recurrence ============================
// (unchanged from round 9)
// A tile: 16 rows x 264 cols bf16 (h only). Valid rows at {0,4,8,12}.
#define ASTR 264
#define ABUF (16 * ASTR)

__global__ __launch_bounds__(256, 1) void ealstm_rec(
    const unsigned short* __restrict__ P,
    const float* __restrict__ c0, const float* __restrict__ h0,
    unsigned short* __restrict__ hs, float* __restrict__ cs,
    const float* __restrict__ Wfh, const float* __restrict__ Wgh, const float* __restrict__ Woh,
    const float* __restrict__ Wout, const float* __restrict__ bout,
    float* __restrict__ out, int t0, int tlen, int first)
{
  __shared__ __attribute__((aligned(16))) short A_sh[2 * ABUF];  // 16896 B
  __shared__ float out_part[2][4][4];                            // 128 B

  const int tid = threadIdx.x;
  const int w   = tid >> 6;   // wave 0..3, owns ch [w*64, w*64+64)
  const int l   = tid & 63;
  const int lr  = l & 15;
  const int lg  = l >> 4;     // activation row = lg (A-row trick)
  const int wg  = blockIdx.x; // 4-row batch block

  // ---- ALL recurrent weights in registers (VGPR+AGPR unified file) ----
  bf16x8 Bf[8][4], Bg[8][4], Bo[8][4];
#pragma unroll
  for (int ks = 0; ks < 8; ++ks) {
#pragma unroll
    for (int nt = 0; nt < 4; ++nt) {
      const int n = w * 64 + nt * 16 + lr;
      const int k = ks * 32 + lg * 8;
      Bf[ks][nt] = loadw8(Wfh + n * HD + k);
      Bg[ks][nt] = loadw8(Wgh + n * HD + k);
      Bo[ks][nt] = loadw8(Woh + n * HD + k);
    }
  }

  // ---- Wout, c-state ----
  float woutv[4], cst[4];
#pragma unroll
  for (int nt = 0; nt < 4; ++nt) {
    const int n = w * 64 + nt * 16 + lr;
    woutv[nt] = Wout[n];
    cst[nt]   = first ? c0[n] : cs[(size_t)(wg * 4 + lg) * 256 + n];
  }
  const float boutv = bout[0];

  // ---- zero both A buffers; stage h-state at A-rows {0,4,8,12} ----
  for (int idx = tid; idx < 2 * ABUF; idx += 256) A_sh[idx] = 0;
  __syncthreads();
  for (int idx = tid; idx < 4 * 256; idx += 256) {
    const int row = idx >> 8, col = idx & 255;
    const short hv = first ? f2bf(h0[col])
                           : (short)hs[(size_t)(wg * 4 + row) * 256 + col];
    A_sh[(4 * row) * ASTR + col] = hv;
  }
  __syncthreads();

  // per-lane P base: row = wg*4+lg, pos = w*16+lr, 16 shorts each
  const unsigned short* Pb = P + ((size_t)(wg * 4 + lg) * tlen) * 1024 + (w * 16 + lr) * 16;
  const int akoff = lg * 8;

  // 2-deep P prefetch
  u32x4 pA0, pB0, pA1, pB1, pA2, pB2;
  pA0 = *reinterpret_cast<const u32x4*>(Pb);
  pB0 = *reinterpret_cast<const u32x4*>(Pb + 8);
  {
    const unsigned short* p1 = Pb + ((tlen > 1) ? 1024 : 0);
    pA1 = *reinterpret_cast<const u32x4*>(p1);
    pB1 = *reinterpret_cast<const u32x4*>(p1 + 8);
  }

  const f32x4 z4 = {0.f, 0.f, 0.f, 0.f};

#pragma unroll 2
  for (int t = 0; t < tlen; ++t) {
    const int cur = t & 1;
    const short* ArowC = A_sh + cur * ABUF + lr * ASTR;
    short* Anxt = A_sh + (cur ^ 1) * ABUF;

    // issue prefetch for t+2 (clamped)
    {
      const int tn = (t + 2 < tlen) ? (t + 2) : (tlen - 1);
      const unsigned short* p2 = Pb + (size_t)tn * 1024;
      pA2 = *reinterpret_cast<const u32x4*>(p2);
      pB2 = *reinterpret_cast<const u32x4*>(p2 + 8);
    }

    // finalize previous step's output (hidden under this step's MFMA phase)
    if (t > 0 && w == 0 && l < 4) {
      float s = boutv;
#pragma unroll
      for (int ww = 0; ww < 4; ++ww) s += out_part[cur ^ 1][l][ww];
      out[(size_t)(wg * 4 + l) * T_LEN + (t0 + t - 1)] = s;
    }

    // ---- K-loop: 1 A-read -> 12 MFMAs; ks=0 folds the acc zero-init ----
    f32x4 acc[3][4];
    {
      const bf16x8 a = *reinterpret_cast<const bf16x8*>(ArowC + akoff);
#pragma unroll
      for (int nt = 0; nt < 4; ++nt)
        acc[0][nt] = __builtin_amdgcn_mfma_f32_16x16x32_bf16(a, Bf[0][nt], z4, 0, 0, 0);
#pragma unroll
      for (int nt = 0; nt < 4; ++nt)
        acc[1][nt] = __builtin_amdgcn_mfma_f32_16x16x32_bf16(a, Bg[0][nt], z4, 0, 0, 0);
#pragma unroll
      for (int nt = 0; nt < 4; ++nt)
        acc[2][nt] = __builtin_amdgcn_mfma_f32_16x16x32_bf16(a, Bo[0][nt], z4, 0, 0, 0);
    }
#pragma unroll
    for (int ks = 1; ks < 8; ++ks) {
      const bf16x8 a = *reinterpret_cast<const bf16x8*>(ArowC + ks * 32 + akoff);
#pragma unroll
      for (int nt = 0; nt < 4; ++nt)
        acc[0][nt] = __builtin_amdgcn_mfma_f32_16x16x32_bf16(a, Bf[ks][nt], acc[0][nt], 0, 0, 0);
#pragma unroll
      for (int nt = 0; nt < 4; ++nt)
        acc[1][nt] = __builtin_amdgcn_mfma_f32_16x16x32_bf16(a, Bg[ks][nt], acc[1][nt], 0, 0, 0);
#pragma unroll
      for (int nt = 0; nt < 4; ++nt)
        acc[2][nt] = __builtin_amdgcn_mfma_f32_16x16x32_bf16(a, Bo[ks][nt], acc[2][nt], 0, 0, 0);
    }

    // ---- activations: 4 gate-sets per lane (row = lg, ch = w*64 + nt*16 + lr) ----
    float po = 0.0f;
#pragma unroll
    for (int nt = 0; nt < 4; ++nt) {
      const float fpre = acc[0][nt][0] + punp16(pA0, 0 + nt);
      const float gpre = acc[1][nt][0] + punp16(pA0, 4 + nt);
      const float opre = acc[2][nt][0] + punp16(pB0, 0 + nt);
      const float iv   = punp16(pB0, 4 + nt);  // sigmoid already applied
      const float sf = sigm(fpre);
      const float tg = tanh_(gpre);
      const float so = sigm(opre);
      const float c  = sf * cst[nt] + iv * tg;
      cst[nt] = c;
      const float hv = so * tanh_(c);
      Anxt[(4 * lg) * ASTR + (w * 64 + nt * 16 + lr)] = f2bf(hv);
      po += so * woutv[nt];
    }

    // po reduce over the 16 lr-lanes -> (row = lg, wave w)
#pragma unroll
    for (int mk = 1; mk < 16; mk <<= 1) {
      po += __shfl_xor(po, mk, 64);
    }
    if (lr == 0) out_part[cur][lg][w] = po;

    // roll P prefetch buffers
    pA0 = pA1; pB0 = pB1;
    pA1 = pA2; pB1 = pB2;

    __syncthreads();  // single per-step barrier
  }

  // final output of the chunk
  if (w == 0 && l < 4) {
    float s = boutv;
#pragma unroll
    for (int ww = 0; ww < 4; ++ww) s += out_part[(tlen - 1) & 1][l][ww];
    out[(size_t)(wg * 4 + l) * T_LEN + (t0 + tlen - 1)] = s;
  }

  // ---- persist c/h state for the next chunk ----
  {
    const short* Afin = A_sh + (tlen & 1) * ABUF;
#pragma unroll
    for (int nt = 0; nt < 4; ++nt) {
      const int n = w * 64 + nt * 16 + lr;
      hs[(size_t)(wg * 4 + lg) * 256 + n] = (unsigned short)Afin[(4 * lg) * ASTR + n];
      cs[(size_t)(wg * 4 + lg) * 256 + n] = cst[nt];
    }
  }
}

// ============================ fallback: round-6 kernel ============================
#define FASTR 296
#define FABUF (16 * FASTR)

__global__ __launch_bounds__(512, 2) void ealstm_fallback(
    const float* __restrict__ x, const float* __restrict__ c0, const float* __restrict__ h0,
    const float* __restrict__ Wi, const float* __restrict__ bi,
    const float* __restrict__ Wfx, const float* __restrict__ bfx,
    const float* __restrict__ Wfh, const float* __restrict__ bfh,
    const float* __restrict__ Wgx, const float* __restrict__ bgx,
    const float* __restrict__ Wgh, const float* __restrict__ bgh,
    const float* __restrict__ Wox, const float* __restrict__ box_,
    const float* __restrict__ Woh, const float* __restrict__ boh,
    const float* __restrict__ Wout, const float* __restrict__ bout,
    float* __restrict__ out)
{
  __shared__ __attribute__((aligned(16))) short A_sh[2 * FABUF];
  __shared__ __attribute__((aligned(16))) short Bo_sh[8 * 16 * 512];
  __shared__ float out_part[2][4][8];

  const int tid = threadIdx.x;
  const int w   = tid >> 6;
  const int l   = tid & 63;
  const int lr  = l & 15;
  const int lg  = l >> 4;
  const int n0  = w * 32;
  const int wg  = blockIdx.x;

  bf16x8 Bf[8][2], Bg[8][2], Bx[4][2];
#pragma unroll
  for (int ks = 0; ks < 8; ++ks) {
#pragma unroll
    for (int nt = 0; nt < 2; ++nt) {
      const int n = n0 + nt * 16 + lr;
      const int k = ks * 32 + lg * 8;
      Bf[ks][nt] = loadw8(Wfh + n * HD + k);
      Bg[ks][nt] = loadw8(Wgh + n * HD + k);
    }
  }
  {
    bf16x8 z = (bf16x8)(short)0;
    const float* WxArr[3] = {Wfx, Wgx, Wox};
#pragma unroll
    for (int nt = 0; nt < 2; ++nt) {
      const int n = n0 + nt * 16 + lr;
#pragma unroll
      for (int g = 0; g < 3; ++g) {
        Bx[g][nt] = (lg == 0) ? loadw8(WxArr[g] + n * 8) : z;
      }
      Bx[3][nt] = (lg >= 1) ? loadw8(Wi + n * 24 + (lg - 1) * 8) : z;
    }
  }

  short* bo = Bo_sh + w * (16 * 512);
#pragma unroll
  for (int ks = 0; ks < 8; ++ks) {
#pragma unroll
    for (int nt = 0; nt < 2; ++nt) {
      const int n = n0 + nt * 16 + lr;
      bf16x8 fr = loadw8(Woh + n * HD + ks * 32 + lg * 8);
      *reinterpret_cast<bf16x8*>(bo + (ks * 2 + nt) * 512 + l * 8) = fr;
    }
  }

  float bias[4][2], woutv[2], cst[2];
#pragma unroll
  for (int nt = 0; nt < 2; ++nt) {
    const int n = n0 + nt * 16 + lr;
    bias[0][nt] = bfx[n] + bfh[n];
    bias[1][nt] = bgx[n] + bgh[n];
    bias[2][nt] = box_[n] + boh[n];
    bias[3][nt] = bi[n];
    woutv[nt] = Wout[n];
    cst[nt] = c0[n];
  }
  const float boutv = bout[0];

  for (int idx = tid; idx < 2 * FABUF; idx += 512) A_sh[idx] = 0;
  __syncthreads();
  for (int idx = tid; idx < 4 * 256; idx += 512) {
    A_sh[(4 * (idx >> 8)) * FASTR + (idx & 255)] = f2bf(h0[idx & 255]);
  }
  if (tid < 128) {
    const int row = tid >> 5, k = tid & 31;
    A_sh[(4 * row) * FASTR + 256 + k] = f2bf(x[((size_t)(wg * 4 + row) * T_LEN) * 32 + k]);
  }
  __syncthreads();

  const float* xp = x + (size_t)(wg * 4 + ((tid >> 5) & 3)) * T_LEN * 32 + (tid & 31);
  const int akoff = lg * 8;

  for (int t = 0; t < T_LEN; ++t) {
    const int cur = t & 1;
    const short* ArowC = A_sh + cur * FABUF + lr * FASTR;
    short* Anxt = A_sh + (cur ^ 1) * FABUF;

    if (t > 0 && w == 0 && l < 4) {
      float s = boutv;
#pragma unroll
      for (int ww = 0; ww < 8; ++ww) s += out_part[cur ^ 1][l][ww];
      out[(size_t)(wg * 4 + l) * T_LEN + (t - 1)] = s;
    }

    float xval = 0.0f;
    if (tid < 128) {
      const int tn = (t + 1 < T_LEN) ? (t + 1) : (T_LEN - 1);
      xval = xp[(size_t)tn * 32];
    }

    f32x4 acc[4][2];
#pragma unroll
    for (int g = 0; g < 4; ++g) {
#pragma unroll
      for (int nt = 0; nt < 2; ++nt) {
        f32x4 v; v[0] = bias[g][nt]; v[1] = bias[g][nt]; v[2] = bias[g][nt]; v[3] = bias[g][nt];
        acc[g][nt] = v;
      }
    }

#pragma unroll
    for (int ks = 0; ks < 8; ++ks) {
      const bf16x8 a = *reinterpret_cast<const bf16x8*>(ArowC + ks * 32 + akoff);
      acc[0][0] = __builtin_amdgcn_mfma_f32_16x16x32_bf16(a, Bf[ks][0], acc[0][0], 0, 0, 0);
      acc[0][1] = __builtin_amdgcn_mfma_f32_16x16x32_bf16(a, Bf[ks][1], acc[0][1], 0, 0, 0);
      acc[1][0] = __builtin_amdgcn_mfma_f32_16x16x32_bf16(a, Bg[ks][0], acc[1][0], 0, 0, 0);
      acc[1][1] = __builtin_amdgcn_mfma_f32_16x16x32_bf16(a, Bg[ks][1], acc[1][1], 0, 0, 0);
    }
    {
      const bf16x8 axv = *reinterpret_cast<const bf16x8*>(ArowC + 256 + akoff);
      acc[3][0] = __builtin_amdgcn_mfma_f32_16x16x32_bf16(axv, Bx[3][0], acc[3][0], 0, 0, 0);
      acc[3][1] = __builtin_amdgcn_mfma_f32_16x16x32_bf16(axv, Bx[3][1], acc[3][1], 0, 0, 0);
      acc[0][0] = __builtin_amdgcn_mfma_f32_16x16x32_bf16(axv, Bx[0][0], acc[0][0], 0, 0, 0);
      acc[0][1] = __builtin_amdgcn_mfma_f32_16x16x32_bf16(axv, Bx[0][1], acc[0][1], 0, 0, 0);
      acc[1][0] = __builtin_amdgcn_mfma_f32_16x16x32_bf16(axv, Bx[1][0], acc[1][0], 0, 0, 0);
      acc[1][1] = __builtin_amdgcn_mfma_f32_16x16x32_bf16(axv, Bx[1][1], acc[1][1], 0, 0, 0);
      acc[2][0] = __builtin_amdgcn_mfma_f32_16x16x32_bf16(axv, Bx[2][0], acc[2][0], 0, 0, 0);
      acc[2][1] = __builtin_amdgcn_mfma_f32_16x16x32_bf16(axv, Bx[2][1], acc[2][1], 0, 0, 0);
    }
#pragma unroll
    for (int ks = 0; ks < 8; ++ks) {
      const bf16x8 a  = *reinterpret_cast<const bf16x8*>(ArowC + ks * 32 + akoff);
      const bf16x8 b0 = *reinterpret_cast<const bf16x8*>(bo + (ks * 2 + 0) * 512 + l * 8);
      const bf16x8 b1 = *reinterpret_cast<const bf16x8*>(bo + (ks * 2 + 1) * 512 + l * 8);
      acc[2][0] = __builtin_amdgcn_mfma_f32_16x16x32_bf16(a, b0, acc[2][0], 0, 0, 0);
      acc[2][1] = __builtin_amdgcn_mfma_f32_16x16x32_bf16(a, b1, acc[2][1], 0, 0, 0);
    }

    float tcv[2];
#pragma unroll
    for (int nt = 0; nt < 2; ++nt) {
      const float sf = sigm(acc[0][nt][0]);
      const float tg = tanh_(acc[1][nt][0]);
      const float si = sigm(acc[3][nt][0]);
      const float c  = sf * cst[nt] + si * tg;
      cst[nt] = c;
      tcv[nt] = tanh_(c);
    }

    float po = 0.0f;
    short hpk[2];
#pragma unroll
    for (int nt = 0; nt < 2; ++nt) {
      const float so = sigm(acc[2][nt][0]);
      const float hv = so * tcv[nt];
      hpk[nt] = f2bf(hv);
      po += so * woutv[nt];
    }

    Anxt[(4 * lg) * FASTR + (n0 + lr)]      = hpk[0];
    Anxt[(4 * lg) * FASTR + (n0 + 16 + lr)] = hpk[1];
    if (tid < 128) Anxt[(4 * (tid >> 5)) * FASTR + 256 + (tid & 31)] = f2bf(xval);

#pragma unroll
    for (int mk = 1; mk < 16; mk <<= 1) {
      po += __shfl_xor(po, mk, 64);
    }
    if (lr == 0) out_part[cur][lg][w] = po;

    __syncthreads();
  }

  if (w == 0 && l < 4) {
    float s = boutv;
#pragma unroll
    for (int ww = 0; ww < 8; ++ww) s += out_part[(T_LEN - 1) & 1][l][ww];
    out[(size_t)(wg * 4 + l) * T_LEN + (T_LEN - 1)] = s;
  }
}

extern "C" void kernel_launch(void* const* d_in, const int* in_sizes, int n_in,
                              void* d_out, int out_size, void* d_ws, size_t ws_size,
                              hipStream_t stream) {
  const float* x    = (const float*)d_in[0];
  const float* c0   = (const float*)d_in[1];
  const float* h0   = (const float*)d_in[2];
  const float* Wi   = (const float*)d_in[3];
  const float* bi   = (const float*)d_in[4];
  const float* Wfx  = (const float*)d_in[5];
  const float* bfx  = (const float*)d_in[6];
  const float* Wfh  = (const float*)d_in[7];
  const float* bfh  = (const float*)d_in[8];
  const float* Wgx  = (const float*)d_in[9];
  const float* bgx  = (const float*)d_in[10];
  const float* Wgh  = (const float*)d_in[11];
  const float* bgh  = (const float*)d_in[12];
  const float* Wox  = (const float*)d_in[13];
  const float* box_ = (const float*)d_in[14];
  const float* Woh  = (const float*)d_in[15];
  const float* boh  = (const float*)d_in[16];
  const float* Wout = (const float*)d_in[17];
  const float* bout = (const float*)d_in[18];

  // ws layout: hs bf16[128*256] @0 (64K); cs f32[128*256] @64K (128K); P @256K.
  const size_t perT = (size_t)128 * 1024 * sizeof(unsigned short);  // 256 KiB per timestep
  const size_t pOff = 262144;

  int TC = 0;
  for (int cand = T_LEN; cand >= 128; cand >>= 1) {
    if (ws_size >= pOff + (size_t)cand * perT) { TC = cand; break; }
  }

  if (TC) {
    unsigned short* hs = (unsigned short*)d_ws;
    float*          cs = (float*)((char*)d_ws + 65536);
    unsigned short* P  = (unsigned short*)((char*)d_ws + pOff);
    for (int t0 = 0; t0 < T_LEN; t0 += TC) {
      precomp_mfma<<<dim3(128, TC / 128), dim3(256), 0, stream>>>(
          x, Wi, bi, Wfx, bfx, bfh, Wgx, bgx, bgh, Wox, box_, boh, P, t0, TC);
      ealstm_rec<<<dim3(32), dim3(256), 0, stream>>>(
          P, c0, h0, hs, cs, Wfh, Wgh, Woh, Wout, bout,
          (float*)d_out, t0, TC, (t0 == 0) ? 1 : 0);
    }
  } else {
    ealstm_fallback<<<dim3(32), dim3(512), 0, stream>>>(
        x, c0, h0, Wi, bi, Wfx, bfx, Wfh, bfh,
        Wgx, bgx, Wgh, bgh, Wox, box_, Woh, boh, Wout, bout,
        (float*)d_out);
  }
}